// Round 2
// baseline (1034.435 us; speedup 1.0000x reference)
//
#include <hip/hip_runtime.h>
#include <math.h>

#define H_ 128
#define W_ 128
#define C_ 64
#define O_ 64
#define B_ 8
#define K2_ 9
#define HWSZ (H_*W_)

// ---------------------------------------------------------------------------
// Kernel T: transpose w (O,C,3,3) -> wt (K2, C, O): sample-GEMM reads weights
// contiguously in o (wave-uniform -> s_load).
// ---------------------------------------------------------------------------
__global__ __launch_bounds__(256) void transpose_w_k(const float* __restrict__ w,
                                                     float* __restrict__ wt) {
    int id = blockIdx.x * 256 + threadIdx.x;   // k*C*O + c*O + o
    if (id >= K2_ * C_ * O_) return;
    int o = id & (O_ - 1);
    int c = (id >> 6) & (C_ - 1);
    int k = id / (C_ * O_);
    wt[id] = w[(o * C_ + c) * K2_ + k];
}

// ---------------------------------------------------------------------------
// Kernel A: 3x3 conv -> 18 offset + 9 mask channels, fused coord calc.
// Block = 512 threads: 256 pixels x 2 channel-halves (c-split for occupancy),
// LDS reduction of the 27 partial sums. blockIdx&7 = batch -> XCD locality.
// ---------------------------------------------------------------------------
__global__ __launch_bounds__(512) void conv_offmask_k(
    const float* __restrict__ x,
    const float* __restrict__ w_off, const float* __restrict__ b_off,
    const float* __restrict__ w_mod, const float* __restrict__ b_mod,
    float* __restrict__ pyA, float* __restrict__ pxA, float* __restrict__ mA) {
    __shared__ float red[27 * 256];            // 27.6 KB

    int b     = blockIdx.x & 7;                // batch -> XCD (L2 locality)
    int strip = blockIdx.x >> 3;               // 0..63 : 2-row strip
    int tid   = threadIdx.x;
    int t     = tid & 255;                     // pixel within strip
    int half  = tid >> 8;                      // 0 or 1 -> channel half
    int p     = strip * 256 + t;               // pixel index within batch
    int w     = p & (W_ - 1);
    int h     = p >> 7;

    int offs[9];
    float valid[9];
#pragma unroll
    for (int i = 0; i < 9; i++) {
        int dy = i / 3 - 1, dx = i % 3 - 1;
        int yy = h + dy, xx = w + dx;
        bool v = (yy >= 0 && yy < H_ && xx >= 0 && xx < W_);
        int yc = min(max(yy, 0), H_ - 1);
        int xc = min(max(xx, 0), W_ - 1);
        offs[i] = yc * W_ + xc;
        valid[i] = v ? 1.0f : 0.0f;
    }

    float acc[27];
#pragma unroll
    for (int o = 0; o < 27; o++) acc[o] = 0.0f;

    int c0 = half * 32;
    const float* xb = x + (b * C_ + c0) * HWSZ;

    for (int c = 0; c < 32; c++) {
        const float* xc = xb + c * HWSZ;
        float v[9];
#pragma unroll
        for (int i = 0; i < 9; i++) v[i] = xc[offs[i]] * valid[i];
        int cg = c0 + c;
        const float* wo = w_off + cg * 9;
#pragma unroll
        for (int o = 0; o < 18; o++) {
#pragma unroll
            for (int k = 0; k < 9; k++) acc[o] += v[k] * wo[o * (C_ * 9) + k];
        }
        const float* wm = w_mod + cg * 9;
#pragma unroll
        for (int o = 0; o < 9; o++) {
#pragma unroll
            for (int k = 0; k < 9; k++) acc[18 + o] += v[k] * wm[o * (C_ * 9) + k];
        }
    }

    if (half) {
#pragma unroll
        for (int o = 0; o < 27; o++) red[o * 256 + t] = acc[o];  // stride-1: no conflicts
    }
    __syncthreads();
    if (!half) {
#pragma unroll
        for (int k = 0; k < 9; k++) {
            float dy = acc[2 * k]     + red[(2 * k)     * 256 + t] + b_off[2 * k];
            float dx = acc[2 * k + 1] + red[(2 * k + 1) * 256 + t] + b_off[2 * k + 1];
            float mm = acc[18 + k]    + red[(18 + k)    * 256 + t] + b_mod[k];
            float mask = 2.0f / (1.0f + __expf(-mm));
            float py = dy + (float)h - 1.0f + (float)(k / 3);
            float px = dx + (float)w - 1.0f + (float)(k % 3);
            int idx = (b * 9 + k) * HWSZ + p;
            pyA[idx] = py;
            pxA[idx] = px;
            mA[idx] = mask;
        }
    }
}

// ---------------------------------------------------------------------------
// Kernel B: bilinear sample + masked reduction GEMM.
// Block = 512 threads: 256 pixels x 2 channel-halves, acc[64] per thread,
// LDS reduce (red[o*256+t] -> conflict-free), coalesced epilogue.
// blockIdx&7 = batch -> per-XCD footprint ~= x[b] = 4.2 MB ~= L2.
// ---------------------------------------------------------------------------
__global__ __launch_bounds__(512) void sample_gemm_k(
    const float* __restrict__ x,
    const float* __restrict__ pyA, const float* __restrict__ pxA,
    const float* __restrict__ mA, const float* __restrict__ wt,
    const float* __restrict__ bias, float* __restrict__ out) {
    __shared__ float red[O_ * 256];            // 64 KB

    int b     = blockIdx.x & 7;
    int strip = blockIdx.x >> 3;
    int tid   = threadIdx.x;
    int t     = tid & 255;
    int half  = tid >> 8;
    int p     = strip * 256 + t;
    int w     = p & (W_ - 1);
    int h     = p >> 7;
    (void)w; (void)h;

    float acc[O_];
#pragma unroll
    for (int o = 0; o < O_; o++) acc[o] = 0.0f;

    int c0 = half * 32;
    const float* xb = x + (b * C_ + c0) * HWSZ;

    for (int k = 0; k < 9; k++) {
        int idx = (b * 9 + k) * HWSZ + p;
        float py = pyA[idx];
        float px = pxA[idx];
        float m  = mA[idx];

        float y0f = floorf(py), x0f = floorf(px);
        float wy = py - y0f, wx = px - x0f;
        int y0 = (int)y0f, x0 = (int)x0f;
        int y1 = y0 + 1, x1 = x0 + 1;
        float vy0 = (y0 >= 0 && y0 < H_) ? 1.0f : 0.0f;
        float vy1 = (y1 >= 0 && y1 < H_) ? 1.0f : 0.0f;
        float vx0 = (x0 >= 0 && x0 < W_) ? 1.0f : 0.0f;
        float vx1 = (x1 >= 0 && x1 < W_) ? 1.0f : 0.0f;
        int y0c = min(max(y0, 0), H_ - 1), y1c = min(max(y1, 0), H_ - 1);
        int x0c = min(max(x0, 0), W_ - 1), x1c = min(max(x1, 0), W_ - 1);

        float w00 = (1.0f - wy) * (1.0f - wx) * vy0 * vx0 * m;
        float w01 = (1.0f - wy) * wx * vy0 * vx1 * m;
        float w10 = wy * (1.0f - wx) * vy1 * vx0 * m;
        float w11 = wy * wx * vy1 * vx1 * m;

        int o00 = y0c * W_ + x0c, o01 = y0c * W_ + x1c;
        int o10 = y1c * W_ + x0c, o11 = y1c * W_ + x1c;

        const float* wp = wt + k * (C_ * O_) + c0 * O_;
        for (int c = 0; c < 32; c++) {
            const float* xc = xb + c * HWSZ;
            float s = w00 * xc[o00] + w01 * xc[o01] + w10 * xc[o10] + w11 * xc[o11];
            const float* wpc = wp + c * O_;
#pragma unroll
            for (int o = 0; o < O_; o++) acc[o] += s * wpc[o];
        }
    }

    if (half) {
#pragma unroll
        for (int o = 0; o < O_; o++) red[o * 256 + t] = acc[o];  // stride-1: no conflicts
    }
    __syncthreads();
    if (!half) {
        int obase = b * O_ * HWSZ + p;
#pragma unroll
        for (int o = 0; o < O_; o++)
            out[obase + o * HWSZ] = acc[o] + red[o * 256 + t] + bias[o];
    }
}

// ---------------------------------------------------------------------------
extern "C" void kernel_launch(void* const* d_in, const int* in_sizes, int n_in,
                              void* d_out, int out_size, void* d_ws, size_t ws_size,
                              hipStream_t stream) {
    const float* x     = (const float*)d_in[0];
    const float* w_off = (const float*)d_in[1];
    const float* b_off = (const float*)d_in[2];
    const float* w_mod = (const float*)d_in[3];
    const float* b_mod = (const float*)d_in[4];
    const float* w     = (const float*)d_in[5];
    const float* bias  = (const float*)d_in[6];
    float* out = (float*)d_out;

    const int nCoord = B_ * K2_ * HWSZ;   // 1,179,648
    float* pyA = (float*)d_ws;
    float* pxA = pyA + nCoord;
    float* mA  = pxA + nCoord;
    float* wt  = mA + nCoord;             // 36,864 floats

    hipLaunchKernelGGL(transpose_w_k, dim3((K2_ * C_ * O_ + 255) / 256), dim3(256),
                       0, stream, w, wt);
    hipLaunchKernelGGL(conv_offmask_k, dim3(512), dim3(512), 0, stream,
                       x, w_off, b_off, w_mod, b_mod, pyA, pxA, mA);
    hipLaunchKernelGGL(sample_gemm_k, dim3(512), dim3(512), 0, stream,
                       x, pyA, pxA, mA, wt, bias, out);
}

// Round 3
// 431.170 us; speedup vs baseline: 2.3991x; 2.3991x over previous
//
#include <hip/hip_runtime.h>
#include <math.h>

#define H_ 128
#define W_ 128
#define C_ 64
#define O_ 64
#define B_ 8
#define K2_ 9
#define HWSZ (H_*W_)

// ---------------------------------------------------------------------------
// Kernel T: transpose w (O,C,3,3) -> wt (K2, C, O): sample-GEMM reads weights
// contiguously in o (wave-uniform -> s_load).
// ---------------------------------------------------------------------------
__global__ __launch_bounds__(256) void transpose_w_k(const float* __restrict__ w,
                                                     float* __restrict__ wt) {
    int id = blockIdx.x * 256 + threadIdx.x;   // k*C*O + c*O + o
    if (id >= K2_ * C_ * O_) return;
    int o = id & (O_ - 1);
    int c = (id >> 6) & (C_ - 1);
    int k = id / (C_ * O_);
    wt[id] = w[(o * C_ + c) * K2_ + k];
}

// ---------------------------------------------------------------------------
// Kernel A: 3x3 conv -> 18 offset + 9 mask channels, fused coord calc.
// Block = 512 threads: 256 pixels x 2 channel-halves, LDS reduce.
// blockIdx&7 = batch -> XCD/L2 locality.
// c0 goes through readfirstlane so the weight pointer chain stays
// provably wave-uniform -> s_load (round-2 regression: divergent c0 turned
// every weight read into a per-lane vector load, 17x VMEM inflation).
// ---------------------------------------------------------------------------
__global__ __launch_bounds__(512) void conv_offmask_k(
    const float* __restrict__ x,
    const float* __restrict__ w_off, const float* __restrict__ b_off,
    const float* __restrict__ w_mod, const float* __restrict__ b_mod,
    float* __restrict__ pyA, float* __restrict__ pxA, float* __restrict__ mA) {
    __shared__ float red[27 * 256];            // 27.6 KB

    int b     = blockIdx.x & 7;                // batch -> XCD (L2 locality)
    int strip = blockIdx.x >> 3;               // 0..63 : 2-row strip
    int tid   = threadIdx.x;
    int t     = tid & 255;                     // pixel within strip
    int half  = tid >> 8;                      // 0 or 1 -> channel half
    int c0    = __builtin_amdgcn_readfirstlane(half << 5);  // wave-uniform SGPR
    int p     = strip * 256 + t;               // pixel index within batch
    int w     = p & (W_ - 1);
    int h     = p >> 7;

    int offs[9];
    float valid[9];
#pragma unroll
    for (int i = 0; i < 9; i++) {
        int dy = i / 3 - 1, dx = i % 3 - 1;
        int yy = h + dy, xx = w + dx;
        bool v = (yy >= 0 && yy < H_ && xx >= 0 && xx < W_);
        int yc = min(max(yy, 0), H_ - 1);
        int xc = min(max(xx, 0), W_ - 1);
        offs[i] = yc * W_ + xc;
        valid[i] = v ? 1.0f : 0.0f;
    }

    float acc[27];
#pragma unroll
    for (int o = 0; o < 27; o++) acc[o] = 0.0f;

    const float* xb = x + (b * C_ + c0) * HWSZ;

    for (int c = 0; c < 32; c++) {
        const float* xc = xb + c * HWSZ;
        float v[9];
#pragma unroll
        for (int i = 0; i < 9; i++) v[i] = xc[offs[i]] * valid[i];
        int cg = c0 + c;                        // SGPR + loop idx -> uniform
        const float* wo = w_off + cg * 9;
#pragma unroll
        for (int o = 0; o < 18; o++) {
#pragma unroll
            for (int k = 0; k < 9; k++) acc[o] += v[k] * wo[o * (C_ * 9) + k];
        }
        const float* wm = w_mod + cg * 9;
#pragma unroll
        for (int o = 0; o < 9; o++) {
#pragma unroll
            for (int k = 0; k < 9; k++) acc[18 + o] += v[k] * wm[o * (C_ * 9) + k];
        }
    }

    if (half) {
#pragma unroll
        for (int o = 0; o < 27; o++) red[o * 256 + t] = acc[o];  // stride-1: no conflicts
    }
    __syncthreads();
    if (!half) {
#pragma unroll
        for (int k = 0; k < 9; k++) {
            float dy = acc[2 * k]     + red[(2 * k)     * 256 + t] + b_off[2 * k];
            float dx = acc[2 * k + 1] + red[(2 * k + 1) * 256 + t] + b_off[2 * k + 1];
            float mm = acc[18 + k]    + red[(18 + k)    * 256 + t] + b_mod[k];
            float mask = 2.0f / (1.0f + __expf(-mm));
            float py = dy + (float)h - 1.0f + (float)(k / 3);
            float px = dx + (float)w - 1.0f + (float)(k % 3);
            int idx = (b * 9 + k) * HWSZ + p;
            pyA[idx] = py;
            pxA[idx] = px;
            mA[idx] = mask;
        }
    }
}

// ---------------------------------------------------------------------------
// Kernel B: bilinear sample + masked reduction GEMM.
// Block = 512 threads: 256 pixels x 2 channel-halves, acc[64]/thread,
// LDS reduce, coalesced epilogue. blockIdx&7 = batch -> XCD/L2 locality.
// c0 via readfirstlane -> weight reads stay s_load (see kernel A note).
// ---------------------------------------------------------------------------
__global__ __launch_bounds__(512) void sample_gemm_k(
    const float* __restrict__ x,
    const float* __restrict__ pyA, const float* __restrict__ pxA,
    const float* __restrict__ mA, const float* __restrict__ wt,
    const float* __restrict__ bias, float* __restrict__ out) {
    __shared__ float red[O_ * 256];            // 64 KB

    int b     = blockIdx.x & 7;
    int strip = blockIdx.x >> 3;
    int tid   = threadIdx.x;
    int t     = tid & 255;
    int half  = tid >> 8;
    int c0    = __builtin_amdgcn_readfirstlane(half << 5);  // wave-uniform SGPR
    int p     = strip * 256 + t;

    float acc[O_];
#pragma unroll
    for (int o = 0; o < O_; o++) acc[o] = 0.0f;

    const float* xb = x + (b * C_ + c0) * HWSZ;

    for (int k = 0; k < 9; k++) {
        int idx = (b * 9 + k) * HWSZ + p;
        float py = pyA[idx];
        float px = pxA[idx];
        float m  = mA[idx];

        float y0f = floorf(py), x0f = floorf(px);
        float wy = py - y0f, wx = px - x0f;
        int y0 = (int)y0f, x0 = (int)x0f;
        int y1 = y0 + 1, x1 = x0 + 1;
        float vy0 = (y0 >= 0 && y0 < H_) ? 1.0f : 0.0f;
        float vy1 = (y1 >= 0 && y1 < H_) ? 1.0f : 0.0f;
        float vx0 = (x0 >= 0 && x0 < W_) ? 1.0f : 0.0f;
        float vx1 = (x1 >= 0 && x1 < W_) ? 1.0f : 0.0f;
        int y0c = min(max(y0, 0), H_ - 1), y1c = min(max(y1, 0), H_ - 1);
        int x0c = min(max(x0, 0), W_ - 1), x1c = min(max(x1, 0), W_ - 1);

        float w00 = (1.0f - wy) * (1.0f - wx) * vy0 * vx0 * m;
        float w01 = (1.0f - wy) * wx * vy0 * vx1 * m;
        float w10 = wy * (1.0f - wx) * vy1 * vx0 * m;
        float w11 = wy * wx * vy1 * vx1 * m;

        int o00 = y0c * W_ + x0c, o01 = y0c * W_ + x1c;
        int o10 = y1c * W_ + x0c, o11 = y1c * W_ + x1c;

        const float* wp = wt + k * (C_ * O_) + c0 * O_;   // uniform -> s_load
        for (int c = 0; c < 32; c++) {
            const float* xc = xb + c * HWSZ;
            float s = w00 * xc[o00] + w01 * xc[o01] + w10 * xc[o10] + w11 * xc[o11];
            const float* wpc = wp + c * O_;
#pragma unroll
            for (int o = 0; o < O_; o++) acc[o] += s * wpc[o];
        }
    }

    if (half) {
#pragma unroll
        for (int o = 0; o < O_; o++) red[o * 256 + t] = acc[o];  // stride-1: no conflicts
    }
    __syncthreads();
    if (!half) {
        int obase = b * O_ * HWSZ + p;
#pragma unroll
        for (int o = 0; o < O_; o++)
            out[obase + o * HWSZ] = acc[o] + red[o * 256 + t] + bias[o];
    }
}

// ---------------------------------------------------------------------------
extern "C" void kernel_launch(void* const* d_in, const int* in_sizes, int n_in,
                              void* d_out, int out_size, void* d_ws, size_t ws_size,
                              hipStream_t stream) {
    const float* x     = (const float*)d_in[0];
    const float* w_off = (const float*)d_in[1];
    const float* b_off = (const float*)d_in[2];
    const float* w_mod = (const float*)d_in[3];
    const float* b_mod = (const float*)d_in[4];
    const float* w     = (const float*)d_in[5];
    const float* bias  = (const float*)d_in[6];
    float* out = (float*)d_out;

    const int nCoord = B_ * K2_ * HWSZ;   // 1,179,648
    float* pyA = (float*)d_ws;
    float* pxA = pyA + nCoord;
    float* mA  = pxA + nCoord;
    float* wt  = mA + nCoord;             // 36,864 floats

    hipLaunchKernelGGL(transpose_w_k, dim3((K2_ * C_ * O_ + 255) / 256), dim3(256),
                       0, stream, w, wt);
    hipLaunchKernelGGL(conv_offmask_k, dim3(512), dim3(512), 0, stream,
                       x, w_off, b_off, w_mod, b_mod, pyA, pxA, mA);
    hipLaunchKernelGGL(sample_gemm_k, dim3(512), dim3(512), 0, stream,
                       x, pyA, pxA, mA, wt, bias, out);
}